// Round 5
// baseline (69.503 us; speedup 1.0000x reference)
//
#include <hip/hip_runtime.h>
#include <math.h>

typedef __bf16 bf16x8 __attribute__((ext_vector_type(8)));
typedef float f32x4 __attribute__((ext_vector_type(4)));

#define N_TOT 8192
#define HALF_N 4096
#define D 128
#define INV_T 14.285714285714286f
#define CSC 20.609929155556627f    /* (1/0.07) * log2(e) */
#define NCSC -20.609929155556627f
#define LN2F 0.69314718055994531f
#define NEG_BIG -3.0e38f
#define M_INIT -1.0e30f
#define CS 16                       /* col chunks of 512; wave covers 128 = 8 tiles */

__device__ __forceinline__ unsigned short f2bf(float f) {
    union { float f; unsigned int u; } a; a.f = f;
    unsigned int u = a.u;
    return (unsigned short)((u + 0x7fffu + ((u >> 16) & 1u)) >> 16);
}

// ---------- kernel 1: fp32 -> bf16 (RNE), 8 elems/thread ----------
__global__ __launch_bounds__(256)
void cvt_kernel(const float* __restrict__ in, unsigned short* __restrict__ fb) {
    const int i = blockIdx.x * 256 + threadIdx.x;
    const float4 v0 = reinterpret_cast<const float4*>(in)[2 * i];
    const float4 v1 = reinterpret_cast<const float4*>(in)[2 * i + 1];
    ushort4 o0, o1;
    o0.x = f2bf(v0.x); o0.y = f2bf(v0.y); o0.z = f2bf(v0.z); o0.w = f2bf(v0.w);
    o1.x = f2bf(v1.x); o1.y = f2bf(v1.y); o1.z = f2bf(v1.z); o1.w = f2bf(v1.w);
    reinterpret_cast<ushort4*>(fb)[2 * i] = o0;
    reinterpret_cast<ushort4*>(fb)[2 * i + 1] = o1;
}

// ---------- kernel 2: fused sim + online logsumexp, pairwise tiles ----------
// grid (128, 16), 256 thr = 4 waves. Block: 64 rows; wave w streams cols
// [by*512 + w*128, +128) as 4 tile-PAIRS. mfma(colfrag, rowfrag): lane's
// f32x4 = 4 consecutive cols of one row; 8-elem batched online-lse update.
__global__ __launch_bounds__(256)
void simclr_kernel(const unsigned short* __restrict__ Fb,
                   float* __restrict__ pm, float* __restrict__ ps,
                   float* __restrict__ rowpos) {
    const int tid  = threadIdx.x;
    const int lane = tid & 63;
    const int wid  = tid >> 6;
    const int lr   = lane & 15;
    const int lg   = lane >> 4;
    const int row0 = blockIdx.x * 64;
    const int c0w  = blockIdx.y * 512 + wid * 128;

    auto ld = [&](int col, int kk) -> bf16x8 {
        return *reinterpret_cast<const bf16x8*>(
            Fb + (size_t)col * D + kk * 32 + lg * 8);
    };

    // held rows (same 64 rows for all 4 waves): 4 row-tiles
    bf16x8 br[4][4];
#pragma unroll
    for (int rt = 0; rt < 4; ++rt)
#pragma unroll
        for (int kk = 0; kk < 4; ++kk)
            br[rt][kk] = ld(row0 + rt * 16 + lr, kk);

    float m[4], s[4];
#pragma unroll
    for (int rt = 0; rt < 4; ++rt) { m[rt] = M_INIT; s[rt] = 0.f; }

    bf16x8 ca[4], cb[4];
#pragma unroll
    for (int kk = 0; kk < 4; ++kk) ca[kk] = ld(c0w + lr, kk);
#pragma unroll
    for (int kk = 0; kk < 4; ++kk) cb[kk] = ld(c0w + 16 + lr, kk);

#pragma unroll 1
    for (int i = 0; i < 4; ++i) {
        const int c0 = c0w + i * 32;          // pair covers cols [c0, c0+32)

        f32x4 accP[4], accQ[4];
#pragma unroll
        for (int rt = 0; rt < 4; ++rt) accP[rt] = f32x4{0.f, 0.f, 0.f, 0.f};
#pragma unroll
        for (int kk = 0; kk < 4; ++kk)
#pragma unroll
            for (int rt = 0; rt < 4; ++rt)
                accP[rt] = __builtin_amdgcn_mfma_f32_16x16x32_bf16(ca[kk], br[rt][kk], accP[rt], 0, 0, 0);
        if (i < 3) {
#pragma unroll
            for (int kk = 0; kk < 4; ++kk) ca[kk] = ld(c0 + 32 + lr, kk);
        }

#pragma unroll
        for (int rt = 0; rt < 4; ++rt) accQ[rt] = f32x4{0.f, 0.f, 0.f, 0.f};
#pragma unroll
        for (int kk = 0; kk < 4; ++kk)
#pragma unroll
            for (int rt = 0; rt < 4; ++rt)
                accQ[rt] = __builtin_amdgcn_mfma_f32_16x16x32_bf16(cb[kk], br[rt][kk], accQ[rt], 0, 0, 0);
        if (i < 3) {
#pragma unroll
            for (int kk = 0; kk < 4; ++kk) cb[kk] = ld(c0 + 48 + lr, kk);
        }

        // merged epilogue over the pair: 8 elems per row per update
#pragma unroll
        for (int rt = 0; rt < 4; ++rt) {
            const int rowbase = row0 + rt * 16;   // lane's row = rowbase + lr
            f32x4 P = accP[rt], Q = accQ[rt];
            if (c0 == (rowbase ^ HALF_N)) {       // wave-uniform
#pragma unroll
                for (int r = 0; r < 4; ++r)
                    if (lr == lg * 4 + r) rowpos[rowbase + lr] = P[r];
            }
            if (c0 + 16 == (rowbase ^ HALF_N)) {
#pragma unroll
                for (int r = 0; r < 4; ++r)
                    if (lr == lg * 4 + r) rowpos[rowbase + lr] = Q[r];
            }
            if (c0 == rowbase) {
#pragma unroll
                for (int r = 0; r < 4; ++r)
                    if (lr == lg * 4 + r) P[r] = NEG_BIG;
            }
            if (c0 + 16 == rowbase) {
#pragma unroll
                for (int r = 0; r < 4; ++r)
                    if (lr == lg * 4 + r) Q[r] = NEG_BIG;
            }
            const float t1 = fmaxf(fmaxf(P[0], P[1]), P[2]);   // v_max3
            const float t2 = fmaxf(fmaxf(P[3], Q[0]), Q[1]);
            const float t3 = fmaxf(Q[2], Q[3]);
            const float rmax = fmaxf(fmaxf(t1, t2), t3);
            const float mo = m[rt];
            const float mn = fmaxf(mo, rmax);                  // raw-dot units
            const float cm = mn * NCSC;
            const float es = __builtin_amdgcn_exp2f(fmaf(mo, CSC, cm));
            const float e0 = __builtin_amdgcn_exp2f(fmaf(P[0], CSC, cm));
            const float e1 = __builtin_amdgcn_exp2f(fmaf(P[1], CSC, cm));
            const float e2 = __builtin_amdgcn_exp2f(fmaf(P[2], CSC, cm));
            const float e3 = __builtin_amdgcn_exp2f(fmaf(P[3], CSC, cm));
            const float e4 = __builtin_amdgcn_exp2f(fmaf(Q[0], CSC, cm));
            const float e5 = __builtin_amdgcn_exp2f(fmaf(Q[1], CSC, cm));
            const float e6 = __builtin_amdgcn_exp2f(fmaf(Q[2], CSC, cm));
            const float e7 = __builtin_amdgcn_exp2f(fmaf(Q[3], CSC, cm));
            const float sum = ((e0 + e1) + (e2 + e3)) + ((e4 + e5) + (e6 + e7));
            s[rt] = fmaf(s[rt], es, sum);
            m[rt] = mn;
        }
    }

    // row-reduce: lanes sharing a row differ only in lg -> 2 shuffles
    __shared__ float red_m[4][64], red_s[4][64];
#pragma unroll
    for (int rt = 0; rt < 4; ++rt) {
        float M = m[rt];
        M = fmaxf(M, __shfl_xor(M, 16, 64));
        M = fmaxf(M, __shfl_xor(M, 32, 64));
        float sc = s[rt] * __builtin_amdgcn_exp2f(fmaf(m[rt], CSC, M * NCSC));
        sc += __shfl_xor(sc, 16, 64);
        sc += __shfl_xor(sc, 32, 64);
        if (lg == 0) { red_m[wid][rt * 16 + lr] = M; red_s[wid][rt * 16 + lr] = sc; }
    }
    __syncthreads();
    if (tid < 64) {   // merge the block's 4 waves (disjoint col ranges)
        float M = red_m[0][tid], S = red_s[0][tid];
#pragma unroll
        for (int w = 1; w < 4; ++w) {
            const float Mo = red_m[w][tid], So = red_s[w][tid];
            const float mn = fmaxf(M, Mo);
            S = fmaf(S,  __builtin_amdgcn_exp2f(fmaf(M,  CSC, mn * NCSC)),
                     So * __builtin_amdgcn_exp2f(fmaf(Mo, CSC, mn * NCSC)));
            M = mn;
        }
        pm[blockIdx.y * N_TOT + row0 + tid] = M;
        ps[blockIdx.y * N_TOT + row0 + tid] = S;
    }
}

// ---------- kernel 3: merge chunks, per-row loss, mean ----------
__global__ __launch_bounds__(1024)
void finalize_kernel(const float* __restrict__ pm, const float* __restrict__ ps,
                     const float* __restrict__ rowpos, float* __restrict__ out) {
    const int tid = threadIdx.x;
    float acc = 0.f;
#pragma unroll 1
    for (int row = tid; row < N_TOT; row += 1024) {
        float M = pm[row], S = ps[row];
#pragma unroll
        for (int c = 1; c < CS; ++c) {
            const float Mo = pm[c * N_TOT + row], So = ps[c * N_TOT + row];
            const float mn = fmaxf(M, Mo);
            S = fmaf(S,  __builtin_amdgcn_exp2f(fmaf(M,  CSC, mn * NCSC)),
                     So * __builtin_amdgcn_exp2f(fmaf(Mo, CSC, mn * NCSC)));
            M = mn;
        }
        acc += LN2F * fmaf(M, CSC, __builtin_amdgcn_logf(S)) - rowpos[row] * INV_T;
    }
#pragma unroll
    for (int off = 32; off > 0; off >>= 1) acc += __shfl_xor(acc, off, 64);
    __shared__ float ls[16];
    if ((tid & 63) == 0) ls[tid >> 6] = acc;
    __syncthreads();
    if (tid == 0) {
        float t = 0.f;
#pragma unroll
        for (int w = 0; w < 16; ++w) t += ls[w];
        out[0] = t * (1.0f / (float)N_TOT);
    }
}

extern "C" void kernel_launch(void* const* d_in, const int* in_sizes, int n_in,
                              void* d_out, int out_size, void* d_ws, size_t ws_size,
                              hipStream_t stream) {
    const float* feat = (const float*)d_in[0];
    char* ws = (char*)d_ws;
    unsigned short* fb = (unsigned short*)ws;                                   // 2 MB
    float* pm     = (float*)(ws + (size_t)N_TOT * D * 2);                       // 512 KB
    float* ps     = (float*)(ws + (size_t)N_TOT * D * 2 + (size_t)CS * N_TOT * 4);        // 512 KB
    float* rowpos = (float*)(ws + (size_t)N_TOT * D * 2 + 2 * (size_t)CS * N_TOT * 4);    // 32 KB
    float* out = (float*)d_out;

    cvt_kernel<<<512, 256, 0, stream>>>(feat, fb);
    simclr_kernel<<<dim3(128, CS), 256, 0, stream>>>(fb, pm, ps, rowpos);
    finalize_kernel<<<1, 1024, 0, stream>>>(pm, ps, rowpos, out);
}

// Round 6
// 49.571 us; speedup vs baseline: 1.4021x; 1.4021x over previous
//
#include <hip/hip_runtime.h>
#include <math.h>

typedef __bf16 bf16x8 __attribute__((ext_vector_type(8)));
typedef float f32x4 __attribute__((ext_vector_type(4)));
typedef unsigned short u16x8 __attribute__((ext_vector_type(8)));

#define N_TOT 8192
#define HALF_N 4096
#define D 128
#define INV_T 14.285714285714286f
#define CSC 20.609929155556627f    /* (1/0.07) * log2(e) */
#define NCSC -20.609929155556627f
#define LN2F 0.69314718055994531f
#define NEG_BIG -3.0e38f
#define M_INIT -1.0e30f
#define CS 8                        /* col chunks of 1024; wave covers 128 cols */

__device__ __forceinline__ unsigned short f2bf(float f) {
    union { float f; unsigned int u; } a; a.f = f;
    unsigned int u = a.u;
    return (unsigned short)((u + 0x7fffu + ((u >> 16) & 1u)) >> 16);
}

// ---------- kernel 1: fp32 -> bf16 packed in MFMA-fragment order ----------
// fbP chunk c (16B = 8 bf16): c = (T*4 + kk)*64 + lg*16 + lr
//   holds F[col = T*16 + lr][ kk*32 + lg*8 .. +8 ]
// so a (tile,kk) fragment load for the whole wave is ONE contiguous 1KB read:
//   fbP16[(T*4+kk)*64 + lane].
__global__ __launch_bounds__(256)
void cvt_kernel(const float* __restrict__ in, unsigned short* __restrict__ fbP) {
    const int c   = blockIdx.x * 256 + threadIdx.x;   // chunk id, coalesced writes
    const int q   = c >> 6;
    const int rem = c & 63;
    const int lg  = rem >> 4, lr = rem & 15;
    const int kk  = q & 3;
    const int col = (q >> 2) * 16 + lr;
    const int j16 = kk * 4 + lg;                      // 16B-chunk index within row
    const float4 v0 = reinterpret_cast<const float4*>(in)[col * 32 + j16 * 2];
    const float4 v1 = reinterpret_cast<const float4*>(in)[col * 32 + j16 * 2 + 1];
    u16x8 o;
    o[0] = f2bf(v0.x); o[1] = f2bf(v0.y); o[2] = f2bf(v0.z); o[3] = f2bf(v0.w);
    o[4] = f2bf(v1.x); o[5] = f2bf(v1.y); o[6] = f2bf(v1.z); o[7] = f2bf(v1.w);
    reinterpret_cast<u16x8*>(fbP)[c] = o;
}

// ---------- kernel 2: fused sim + online logsumexp ----------
// grid (128, 8), 512 thr = 8 waves. Block: 64 shared held rows; wave w streams
// cols [by*1024 + w*128, +128) as 4 tile-pairs. All loads contiguous 1KB/wave.
__global__ __launch_bounds__(512)
void simclr_kernel(const unsigned short* __restrict__ fbP,
                   float* __restrict__ pm, float* __restrict__ ps,
                   float* __restrict__ rowpos) {
    const int tid  = threadIdx.x;
    const int lane = tid & 63;
    const int wid  = tid >> 6;              // 0..7
    const int lr   = lane & 15;
    const int lg   = lane >> 4;
    const int row0 = blockIdx.x * 64;
    const int c0w  = blockIdx.y * 1024 + wid * 128;
    const int Tw   = c0w >> 4;              // first col-tile index for this wave

    auto ld16 = [&](int chunk) -> bf16x8 {
        return *reinterpret_cast<const bf16x8*>(fbP + (size_t)chunk * 8);
    };

    // held rows (same 64 rows for all 8 waves -> L1-shared)
    bf16x8 br[4][4];
#pragma unroll
    for (int rt = 0; rt < 4; ++rt)
#pragma unroll
        for (int kk = 0; kk < 4; ++kk)
            br[rt][kk] = ld16(((blockIdx.x * 4 + rt) * 4 + kk) * 64 + lane);

    float m[4], s[4];
#pragma unroll
    for (int rt = 0; rt < 4; ++rt) { m[rt] = M_INIT; s[rt] = 0.f; }

    bf16x8 ca[4], cb[4];
#pragma unroll
    for (int kk = 0; kk < 4; ++kk) ca[kk] = ld16((Tw * 4 + kk) * 64 + lane);
#pragma unroll
    for (int kk = 0; kk < 4; ++kk) cb[kk] = ld16(((Tw + 1) * 4 + kk) * 64 + lane);

#pragma unroll 1
    for (int i = 0; i < 4; ++i) {
        const int c0 = c0w + i * 32;          // pair covers cols [c0, c0+32)

        f32x4 accP[4], accQ[4];
#pragma unroll
        for (int rt = 0; rt < 4; ++rt) accP[rt] = f32x4{0.f, 0.f, 0.f, 0.f};
#pragma unroll
        for (int kk = 0; kk < 4; ++kk)
#pragma unroll
            for (int rt = 0; rt < 4; ++rt)
                accP[rt] = __builtin_amdgcn_mfma_f32_16x16x32_bf16(ca[kk], br[rt][kk], accP[rt], 0, 0, 0);
        if (i < 3) {
#pragma unroll
            for (int kk = 0; kk < 4; ++kk)
                ca[kk] = ld16(((Tw + 2 * i + 2) * 4 + kk) * 64 + lane);
        }

#pragma unroll
        for (int rt = 0; rt < 4; ++rt) accQ[rt] = f32x4{0.f, 0.f, 0.f, 0.f};
#pragma unroll
        for (int kk = 0; kk < 4; ++kk)
#pragma unroll
            for (int rt = 0; rt < 4; ++rt)
                accQ[rt] = __builtin_amdgcn_mfma_f32_16x16x32_bf16(cb[kk], br[rt][kk], accQ[rt], 0, 0, 0);
        if (i < 3) {
#pragma unroll
            for (int kk = 0; kk < 4; ++kk)
                cb[kk] = ld16(((Tw + 2 * i + 3) * 4 + kk) * 64 + lane);
        }

        // merged pair epilogue: lane's elems = sim[row0+rt*16+lr][c0 + lg*4+r (+16)]
#pragma unroll
        for (int rt = 0; rt < 4; ++rt) {
            const int rowbase = row0 + rt * 16;
            f32x4 P = accP[rt], Q = accQ[rt];
            if (c0 == (rowbase ^ HALF_N)) {       // wave-uniform: positive tile
#pragma unroll
                for (int r = 0; r < 4; ++r)
                    if (lr == lg * 4 + r) rowpos[rowbase + lr] = P[r];
            }
            if (c0 + 16 == (rowbase ^ HALF_N)) {
#pragma unroll
                for (int r = 0; r < 4; ++r)
                    if (lr == lg * 4 + r) rowpos[rowbase + lr] = Q[r];
            }
            if (c0 == rowbase) {                  // wave-uniform: diagonal tile
#pragma unroll
                for (int r = 0; r < 4; ++r)
                    if (lr == lg * 4 + r) P[r] = NEG_BIG;
            }
            if (c0 + 16 == rowbase) {
#pragma unroll
                for (int r = 0; r < 4; ++r)
                    if (lr == lg * 4 + r) Q[r] = NEG_BIG;
            }
            const float t1 = fmaxf(fmaxf(P[0], P[1]), P[2]);
            const float t2 = fmaxf(fmaxf(P[3], Q[0]), Q[1]);
            const float t3 = fmaxf(Q[2], Q[3]);
            const float rmax = fmaxf(fmaxf(t1, t2), t3);
            const float mo = m[rt];
            const float mn = fmaxf(mo, rmax);
            const float cm = mn * NCSC;
            const float es = __builtin_amdgcn_exp2f(fmaf(mo, CSC, cm));
            const float e0 = __builtin_amdgcn_exp2f(fmaf(P[0], CSC, cm));
            const float e1 = __builtin_amdgcn_exp2f(fmaf(P[1], CSC, cm));
            const float e2 = __builtin_amdgcn_exp2f(fmaf(P[2], CSC, cm));
            const float e3 = __builtin_amdgcn_exp2f(fmaf(P[3], CSC, cm));
            const float e4 = __builtin_amdgcn_exp2f(fmaf(Q[0], CSC, cm));
            const float e5 = __builtin_amdgcn_exp2f(fmaf(Q[1], CSC, cm));
            const float e6 = __builtin_amdgcn_exp2f(fmaf(Q[2], CSC, cm));
            const float e7 = __builtin_amdgcn_exp2f(fmaf(Q[3], CSC, cm));
            const float sum = ((e0 + e1) + (e2 + e3)) + ((e4 + e5) + (e6 + e7));
            s[rt] = fmaf(s[rt], es, sum);
            m[rt] = mn;
        }
    }

    // row-reduce: lanes sharing a row differ only in lg -> 2 shuffles
    __shared__ float red_m[8][64], red_s[8][64];
#pragma unroll
    for (int rt = 0; rt < 4; ++rt) {
        float M = m[rt];
        M = fmaxf(M, __shfl_xor(M, 16, 64));
        M = fmaxf(M, __shfl_xor(M, 32, 64));
        float sc = s[rt] * __builtin_amdgcn_exp2f(fmaf(m[rt], CSC, M * NCSC));
        sc += __shfl_xor(sc, 16, 64);
        sc += __shfl_xor(sc, 32, 64);
        if (lg == 0) { red_m[wid][rt * 16 + lr] = M; red_s[wid][rt * 16 + lr] = sc; }
    }
    __syncthreads();
    if (tid < 64) {   // merge the block's 8 waves (disjoint col ranges)
        float M = red_m[0][tid], S = red_s[0][tid];
#pragma unroll
        for (int w = 1; w < 8; ++w) {
            const float Mo = red_m[w][tid], So = red_s[w][tid];
            const float mn = fmaxf(M, Mo);
            S = fmaf(S,  __builtin_amdgcn_exp2f(fmaf(M,  CSC, mn * NCSC)),
                     So * __builtin_amdgcn_exp2f(fmaf(Mo, CSC, mn * NCSC)));
            M = mn;
        }
        pm[blockIdx.y * N_TOT + row0 + tid] = M;
        ps[blockIdx.y * N_TOT + row0 + tid] = S;
    }
}

// ---------- kernel 3: merge chunks, per-row loss, mean ----------
__global__ __launch_bounds__(1024)
void finalize_kernel(const float* __restrict__ pm, const float* __restrict__ ps,
                     const float* __restrict__ rowpos, float* __restrict__ out) {
    const int tid = threadIdx.x;
    float acc = 0.f;
#pragma unroll 1
    for (int row = tid; row < N_TOT; row += 1024) {
        float M = pm[row], S = ps[row];
#pragma unroll
        for (int c = 1; c < CS; ++c) {
            const float Mo = pm[c * N_TOT + row], So = ps[c * N_TOT + row];
            const float mn = fmaxf(M, Mo);
            S = fmaf(S,  __builtin_amdgcn_exp2f(fmaf(M,  CSC, mn * NCSC)),
                     So * __builtin_amdgcn_exp2f(fmaf(Mo, CSC, mn * NCSC)));
            M = mn;
        }
        acc += LN2F * fmaf(M, CSC, __builtin_amdgcn_logf(S)) - rowpos[row] * INV_T;
    }
#pragma unroll
    for (int off = 32; off > 0; off >>= 1) acc += __shfl_xor(acc, off, 64);
    __shared__ float ls[16];
    if ((tid & 63) == 0) ls[tid >> 6] = acc;
    __syncthreads();
    if (tid == 0) {
        float t = 0.f;
#pragma unroll
        for (int w = 0; w < 16; ++w) t += ls[w];
        out[0] = t * (1.0f / (float)N_TOT);
    }
}

extern "C" void kernel_launch(void* const* d_in, const int* in_sizes, int n_in,
                              void* d_out, int out_size, void* d_ws, size_t ws_size,
                              hipStream_t stream) {
    const float* feat = (const float*)d_in[0];
    char* ws = (char*)d_ws;
    unsigned short* fbP = (unsigned short*)ws;                                  // 2 MB
    float* pm     = (float*)(ws + (size_t)N_TOT * D * 2);                       // 256 KB
    float* ps     = (float*)(ws + (size_t)N_TOT * D * 2 + (size_t)CS * N_TOT * 4);        // 256 KB
    float* rowpos = (float*)(ws + (size_t)N_TOT * D * 2 + 2 * (size_t)CS * N_TOT * 4);    // 32 KB
    float* out = (float*)d_out;

    cvt_kernel<<<512, 256, 0, stream>>>(feat, fbP);
    simclr_kernel<<<dim3(128, CS), 512, 0, stream>>>(fbP, pm, ps, rowpos);
    finalize_kernel<<<1, 1024, 0, stream>>>(pm, ps, rowpos, out);
}

// Round 7
// 45.257 us; speedup vs baseline: 1.5357x; 1.0953x over previous
//
#include <hip/hip_runtime.h>
#include <math.h>

typedef __bf16 bf16x8 __attribute__((ext_vector_type(8)));
typedef float f32x4 __attribute__((ext_vector_type(4)));
typedef unsigned short u16x8 __attribute__((ext_vector_type(8)));

#define N_TOT 8192
#define HALF_N 4096
#define D 128
#define INV_T 14.285714285714286f
#define CSC 20.609929155556627f    /* (1/0.07) * log2(e) */
#define NCSC -20.609929155556627f
#define LN2F 0.69314718055994531f
#define NEG_BIG -3.0e38f
#define M_INIT -1.0e30f
#define CS 16                       /* col groups of 512 */

__device__ __forceinline__ unsigned short f2bf(float f) {
    union { float f; unsigned int u; } a; a.f = f;
    unsigned int u = a.u;
    return (unsigned short)((u + 0x7fffu + ((u >> 16) & 1u)) >> 16);
}

// ---------- kernel 1: fp32 -> bf16 packed in MFMA-fragment order ----------
// fbP chunk c (16B): c = (T*4 + kk)*64 + lg*16 + lr  holds
// F[col = T*16 + lr][kk*32 + lg*8 .. +8]; a (tile,kk) wave-load is one
// contiguous 1KB read: chunk (T*4+kk)*64 + lane.
__global__ __launch_bounds__(256)
void cvt_kernel(const float* __restrict__ in, unsigned short* __restrict__ fbP) {
    const int c   = blockIdx.x * 256 + threadIdx.x;
    const int q   = c >> 6;
    const int rem = c & 63;
    const int lg  = rem >> 4, lr = rem & 15;
    const int kk  = q & 3;
    const int col = (q >> 2) * 16 + lr;
    const int j16 = kk * 4 + lg;
    const float4 v0 = reinterpret_cast<const float4*>(in)[col * 32 + j16 * 2];
    const float4 v1 = reinterpret_cast<const float4*>(in)[col * 32 + j16 * 2 + 1];
    u16x8 o;
    o[0] = f2bf(v0.x); o[1] = f2bf(v0.y); o[2] = f2bf(v0.z); o[3] = f2bf(v0.w);
    o[4] = f2bf(v1.x); o[5] = f2bf(v1.y); o[6] = f2bf(v1.z); o[7] = f2bf(v1.w);
    reinterpret_cast<u16x8*>(fbP)[c] = o;
}

// ---------- kernel 2: fused sim + online logsumexp ----------
// grid (16 rowgroups, 16 colgroups), 512 thr = 8 waves, 1 block/CU.
// Wave w HOLDS rows [rg*512 + w*64, +64); all 8 waves STREAM the same
// cols [cg*512, +512) as 16 tile-pairs -> L1-shared streamed fragments.
// Waves own disjoint rows: no cross-wave merge, no LDS, no syncthreads.
__global__ __launch_bounds__(512)
void simclr_kernel(const unsigned short* __restrict__ fbP,
                   float* __restrict__ pm, float* __restrict__ ps,
                   float* __restrict__ rowpos) {
    const int tid  = threadIdx.x;
    const int lane = tid & 63;
    const int wid  = tid >> 6;              // 0..7
    const int lr   = lane & 15;
    const int lg   = lane >> 4;
    const int RT0  = blockIdx.x * 32 + wid * 4;   // first held row-tile
    const int Tw   = blockIdx.y * 32;             // first streamed col-tile

    auto ld16 = [&](int chunk) -> bf16x8 {
        return *reinterpret_cast<const bf16x8*>(fbP + (size_t)chunk * 8);
    };

    // held rows: 4 row-tiles (distinct per wave)
    bf16x8 br[4][4];
#pragma unroll
    for (int rt = 0; rt < 4; ++rt)
#pragma unroll
        for (int kk = 0; kk < 4; ++kk)
            br[rt][kk] = ld16(((RT0 + rt) * 4 + kk) * 64 + lane);

    float m[4], s[4];
#pragma unroll
    for (int rt = 0; rt < 4; ++rt) { m[rt] = M_INIT; s[rt] = 0.f; }

    bf16x8 ca[4], cb[4];
#pragma unroll
    for (int kk = 0; kk < 4; ++kk) ca[kk] = ld16((Tw * 4 + kk) * 64 + lane);
#pragma unroll
    for (int kk = 0; kk < 4; ++kk) cb[kk] = ld16(((Tw + 1) * 4 + kk) * 64 + lane);

#pragma unroll 1
    for (int i = 0; i < 16; ++i) {
        const int c0 = blockIdx.y * 512 + i * 32;   // pair covers [c0, c0+32)

        f32x4 accP[4], accQ[4];
#pragma unroll
        for (int rt = 0; rt < 4; ++rt) accP[rt] = f32x4{0.f, 0.f, 0.f, 0.f};
#pragma unroll
        for (int kk = 0; kk < 4; ++kk)
#pragma unroll
            for (int rt = 0; rt < 4; ++rt)
                accP[rt] = __builtin_amdgcn_mfma_f32_16x16x32_bf16(ca[kk], br[rt][kk], accP[rt], 0, 0, 0);
        if (i < 15) {
#pragma unroll
            for (int kk = 0; kk < 4; ++kk)
                ca[kk] = ld16(((Tw + 2 * i + 2) * 4 + kk) * 64 + lane);
        }

#pragma unroll
        for (int rt = 0; rt < 4; ++rt) accQ[rt] = f32x4{0.f, 0.f, 0.f, 0.f};
#pragma unroll
        for (int kk = 0; kk < 4; ++kk)
#pragma unroll
            for (int rt = 0; rt < 4; ++rt)
                accQ[rt] = __builtin_amdgcn_mfma_f32_16x16x32_bf16(cb[kk], br[rt][kk], accQ[rt], 0, 0, 0);
        if (i < 15) {
#pragma unroll
            for (int kk = 0; kk < 4; ++kk)
                cb[kk] = ld16(((Tw + 2 * i + 3) * 4 + kk) * 64 + lane);
        }

        // merged pair epilogue: lane's elems = sim[rowbase+lr][c0 + lg*4+r (+16)]
#pragma unroll
        for (int rt = 0; rt < 4; ++rt) {
            const int rowbase = (RT0 + rt) * 16;
            f32x4 P = accP[rt], Q = accQ[rt];
            if (c0 == (rowbase ^ HALF_N)) {       // wave-uniform: positive tile
#pragma unroll
                for (int r = 0; r < 4; ++r)
                    if (lr == lg * 4 + r) rowpos[rowbase + lr] = P[r];
            }
            if (c0 + 16 == (rowbase ^ HALF_N)) {
#pragma unroll
                for (int r = 0; r < 4; ++r)
                    if (lr == lg * 4 + r) rowpos[rowbase + lr] = Q[r];
            }
            if (c0 == rowbase) {                  // wave-uniform: diagonal tile
#pragma unroll
                for (int r = 0; r < 4; ++r)
                    if (lr == lg * 4 + r) P[r] = NEG_BIG;
            }
            if (c0 + 16 == rowbase) {
#pragma unroll
                for (int r = 0; r < 4; ++r)
                    if (lr == lg * 4 + r) Q[r] = NEG_BIG;
            }
            const float t1 = fmaxf(fmaxf(P[0], P[1]), P[2]);
            const float t2 = fmaxf(fmaxf(P[3], Q[0]), Q[1]);
            const float t3 = fmaxf(Q[2], Q[3]);
            const float rmax = fmaxf(fmaxf(t1, t2), t3);
            const float mo = m[rt];
            const float mn = fmaxf(mo, rmax);
            const float cm = mn * NCSC;
            const float es = __builtin_amdgcn_exp2f(fmaf(mo, CSC, cm));
            const float e0 = __builtin_amdgcn_exp2f(fmaf(P[0], CSC, cm));
            const float e1 = __builtin_amdgcn_exp2f(fmaf(P[1], CSC, cm));
            const float e2 = __builtin_amdgcn_exp2f(fmaf(P[2], CSC, cm));
            const float e3 = __builtin_amdgcn_exp2f(fmaf(P[3], CSC, cm));
            const float e4 = __builtin_amdgcn_exp2f(fmaf(Q[0], CSC, cm));
            const float e5 = __builtin_amdgcn_exp2f(fmaf(Q[1], CSC, cm));
            const float e6 = __builtin_amdgcn_exp2f(fmaf(Q[2], CSC, cm));
            const float e7 = __builtin_amdgcn_exp2f(fmaf(Q[3], CSC, cm));
            const float sum = ((e0 + e1) + (e2 + e3)) + ((e4 + e5) + (e6 + e7));
            s[rt] = fmaf(s[rt], es, sum);
            m[rt] = mn;
        }
    }

    // per-wave row-reduce: lanes sharing a row differ only in lg (xor 16,32)
#pragma unroll
    for (int rt = 0; rt < 4; ++rt) {
        float M = m[rt];
        M = fmaxf(M, __shfl_xor(M, 16, 64));
        M = fmaxf(M, __shfl_xor(M, 32, 64));
        float sc = s[rt] * __builtin_amdgcn_exp2f(fmaf(m[rt], CSC, M * NCSC));
        sc += __shfl_xor(sc, 16, 64);
        sc += __shfl_xor(sc, 32, 64);
        if (lg == 0) {
            const int row = (RT0 + rt) * 16 + lr;
            pm[blockIdx.y * N_TOT + row] = M;
            ps[blockIdx.y * N_TOT + row] = sc;
        }
    }
}

// ---------- kernel 3a: merge col-group partials -> per-row loss ----------
__global__ __launch_bounds__(256)
void rowloss_kernel(const float* __restrict__ pm, const float* __restrict__ ps,
                    const float* __restrict__ rowpos, float* __restrict__ rowloss) {
    const int row = blockIdx.x * 256 + threadIdx.x;
    float M = pm[row], S = ps[row];
#pragma unroll
    for (int c = 1; c < CS; ++c) {
        const float Mo = pm[c * N_TOT + row], So = ps[c * N_TOT + row];
        const float mn = fmaxf(M, Mo);
        S = fmaf(S,  __builtin_amdgcn_exp2f(fmaf(M,  CSC, mn * NCSC)),
                 So * __builtin_amdgcn_exp2f(fmaf(Mo, CSC, mn * NCSC)));
        M = mn;
    }
    rowloss[row] = LN2F * fmaf(M, CSC, __builtin_amdgcn_logf(S)) - rowpos[row] * INV_T;
}

// ---------- kernel 3b: mean ----------
__global__ __launch_bounds__(256)
void mean_kernel(const float* __restrict__ rowloss, float* __restrict__ out) {
    float acc = 0.f;
    for (int i = threadIdx.x; i < N_TOT; i += 256) acc += rowloss[i];
#pragma unroll
    for (int off = 32; off > 0; off >>= 1) acc += __shfl_xor(acc, off, 64);
    __shared__ float ls[4];
    if ((threadIdx.x & 63) == 0) ls[threadIdx.x >> 6] = acc;
    __syncthreads();
    if (threadIdx.x == 0)
        out[0] = (ls[0] + ls[1] + ls[2] + ls[3]) * (1.0f / (float)N_TOT);
}

extern "C" void kernel_launch(void* const* d_in, const int* in_sizes, int n_in,
                              void* d_out, int out_size, void* d_ws, size_t ws_size,
                              hipStream_t stream) {
    const float* feat = (const float*)d_in[0];
    char* ws = (char*)d_ws;
    unsigned short* fbP = (unsigned short*)ws;                                  // 2 MB
    float* pm      = (float*)(ws + (size_t)N_TOT * D * 2);                      // 512 KB
    float* ps      = (float*)(ws + (size_t)N_TOT * D * 2 + (size_t)CS * N_TOT * 4);       // 512 KB
    float* rowpos  = (float*)(ws + (size_t)N_TOT * D * 2 + 2 * (size_t)CS * N_TOT * 4);   // 32 KB
    float* rowloss = (float*)(ws + (size_t)N_TOT * D * 2 + 2 * (size_t)CS * N_TOT * 4 + N_TOT * 4);
    float* out = (float*)d_out;

    cvt_kernel<<<512, 256, 0, stream>>>(feat, fbP);
    simclr_kernel<<<dim3(16, CS), 512, 0, stream>>>(fbP, pm, ps, rowpos);
    rowloss_kernel<<<N_TOT / 256, 256, 0, stream>>>(pm, ps, rowpos, rowloss);
    mean_kernel<<<1, 256, 0, stream>>>(rowloss, out);
}